// Round 1
// 1531.241 us; speedup vs baseline: 3.0712x; 3.0712x over previous
//
#include <hip/hip_runtime.h>

// Problem constants (fixed by the reference file).
#define N_NODES 65536
#define D_FEAT  256
#define SCAN_B  256   // two-level scan: 256 blocks x 256 threads == N_NODES

// out layout (float32): [0,N) node_ids | [N, N+N*D) mean messages | [N+N*D, +N) ts max
// ws  layout (u32):     counts[N] | ofs[N] | cursor[N] | partial[256] | base[256] | sorted[E]

// ---------------------------------------------------------------------------
// 1. init: node_ids, ts-max identity (timestamps >= 0), zero counts.
//    Means region needs no init: reduce_kernel writes every element exactly once.
__global__ void init_kernel(float* __restrict__ out, unsigned* __restrict__ counts) {
    const int i = blockIdx.x * blockDim.x + threadIdx.x;   // grid covers exactly N
    out[i] = (float)i;                                     // node_ids as float values
    out[N_NODES + (size_t)N_NODES * D_FEAT + i] = 0.0f;    // ts identity
    counts[i] = 0u;
}

// ---------------------------------------------------------------------------
// 2. histogram of node ids + fused timestamp max.
//    Both atomic targets are 256 KB -> L2-resident, low contention (avg 16/node).
__global__ void hist_kernel(const int* __restrict__ node_index,
                            const float* __restrict__ timestamp,
                            unsigned* __restrict__ counts,
                            unsigned* __restrict__ ts_bits,
                            int E) {
    const int e = blockIdx.x * blockDim.x + threadIdx.x;
    if (e >= E) return;
    const int idx = node_index[e];
    atomicAdd(&counts[idx], 1u);
    // positive IEEE floats compare identically as uints
    atomicMax(&ts_bits[idx], __float_as_uint(timestamp[e]));
}

// ---------------------------------------------------------------------------
// 3a. per-block sums of counts (256 blocks x 256 threads).
__global__ void scan_block_sums(const unsigned* __restrict__ counts,
                                unsigned* __restrict__ partial) {
    __shared__ unsigned s[SCAN_B];
    const int t = threadIdx.x, b = blockIdx.x;
    s[t] = counts[b * SCAN_B + t];
    __syncthreads();
    for (int off = SCAN_B / 2; off > 0; off >>= 1) {
        if (t < off) s[t] += s[t + off];
        __syncthreads();
    }
    if (t == 0) partial[b] = s[0];
}

// 3b. exclusive scan of the 256 block sums (single block).
__global__ void scan_top(const unsigned* __restrict__ partial,
                         unsigned* __restrict__ base) {
    __shared__ unsigned s[SCAN_B];
    const int t = threadIdx.x;
    s[t] = partial[t];
    __syncthreads();
    for (int off = 1; off < SCAN_B; off <<= 1) {       // Hillis-Steele inclusive
        unsigned v = 0;
        if (t >= off) v = s[t - off];
        __syncthreads();
        if (t >= off) s[t] += v;
        __syncthreads();
    }
    base[t] = (t == 0) ? 0u : s[t - 1];                // shift -> exclusive
}

// 3c. final exclusive offsets; write both ofs (read-only) and cursor (atomic).
__global__ void scan_final(const unsigned* __restrict__ counts,
                           const unsigned* __restrict__ base,
                           unsigned* __restrict__ ofs,
                           unsigned* __restrict__ cursor) {
    __shared__ unsigned s[SCAN_B];
    const int t = threadIdx.x, b = blockIdx.x;
    const unsigned c = counts[b * SCAN_B + t];
    s[t] = c;
    __syncthreads();
    for (int off = 1; off < SCAN_B; off <<= 1) {       // Hillis-Steele inclusive
        unsigned v = 0;
        if (t >= off) v = s[t - off];
        __syncthreads();
        if (t >= off) s[t] += v;
        __syncthreads();
    }
    const unsigned val = base[b] + (s[t] - c);         // inclusive - own = exclusive
    const int i = b * SCAN_B + t;
    ofs[i]    = val;
    cursor[i] = val;
}

// ---------------------------------------------------------------------------
// 4. counting-sort scatter of EVENT IDS (4 B each, not the 1 KiB rows).
__global__ void scatter_idx_kernel(const int* __restrict__ node_index,
                                   unsigned* __restrict__ cursor,
                                   unsigned* __restrict__ sorted,
                                   int E) {
    const int e = blockIdx.x * blockDim.x + threadIdx.x;
    if (e >= E) return;
    const int idx = node_index[e];
    const unsigned pos = atomicAdd(&cursor[idx], 1u);
    sorted[pos] = (unsigned)e;
}

// ---------------------------------------------------------------------------
// 5. wave-per-node gather-reduce. Each 1 KiB message row is read exactly once,
//    fully coalesced (lane i -> float4 i of the row); output written once.
__global__ __launch_bounds__(256) void reduce_kernel(const float4* __restrict__ msg4,
                                                     const unsigned* __restrict__ sorted,
                                                     const unsigned* __restrict__ ofs,
                                                     const unsigned* __restrict__ counts,
                                                     float* __restrict__ out) {
    const int node = (blockIdx.x << 2) + (threadIdx.x >> 6);   // one wave per node
    const int lane = threadIdx.x & 63;

    const unsigned start = ofs[node];     // wave-uniform -> broadcast
    const unsigned cnt   = counts[node];

    float4 a0 = make_float4(0.f, 0.f, 0.f, 0.f);
    float4 a1 = make_float4(0.f, 0.f, 0.f, 0.f);

    for (unsigned b = 0; b < cnt; b += 64) {
        const int m = (int)min(64u, cnt - b);
        int eid = 0;
        if (lane < m) eid = (int)sorted[start + b + lane];  // lane-parallel id load
        int j = 0;
        for (; j + 1 < m; j += 2) {                         // 2-deep load pipeline
            const int e0 = __shfl(eid, j);
            const int e1 = __shfl(eid, j + 1);
            const float4 v0 = msg4[(size_t)e0 * 64 + lane];
            const float4 v1 = msg4[(size_t)e1 * 64 + lane];
            a0.x += v0.x; a0.y += v0.y; a0.z += v0.z; a0.w += v0.w;
            a1.x += v1.x; a1.y += v1.y; a1.z += v1.z; a1.w += v1.w;
        }
        if (j < m) {
            const int e0 = __shfl(eid, j);
            const float4 v0 = msg4[(size_t)e0 * 64 + lane];
            a0.x += v0.x; a0.y += v0.y; a0.z += v0.z; a0.w += v0.w;
        }
    }

    const float inv = (cnt > 0u) ? (1.0f / (float)cnt) : 0.0f;
    float4 r;
    r.x = (a0.x + a1.x) * inv;
    r.y = (a0.y + a1.y) * inv;
    r.z = (a0.z + a1.z) * inv;
    r.w = (a0.w + a1.w) * inv;
    ((float4*)(out + N_NODES))[(size_t)node * 64 + lane] = r;
}

// ---------------------------------------------------------------------------
extern "C" void kernel_launch(void* const* d_in, const int* in_sizes, int n_in,
                              void* d_out, int out_size, void* d_ws, size_t ws_size,
                              hipStream_t stream) {
    const float* messages   = (const float*)d_in[0];
    const float* timestamp  = (const float*)d_in[1];
    const int*   node_index = (const int*)d_in[2];
    const int E = in_sizes[2];

    float* out = (float*)d_out;
    unsigned* ws      = (unsigned*)d_ws;
    unsigned* counts  = ws;                              // N
    unsigned* ofs     = ws + N_NODES;                    // N
    unsigned* cursor  = ws + 2 * (size_t)N_NODES;        // N
    unsigned* partial = ws + 3 * (size_t)N_NODES;        // 256
    unsigned* base    = ws + 3 * (size_t)N_NODES + SCAN_B;       // 256
    unsigned* sorted  = ws + 3 * (size_t)N_NODES + 2 * SCAN_B;   // E

    unsigned* ts_bits = (unsigned*)(out + N_NODES + (size_t)N_NODES * D_FEAT);

    const int eblocks = (E + 255) / 256;

    init_kernel<<<N_NODES / 256, 256, 0, stream>>>(out, counts);
    hist_kernel<<<eblocks, 256, 0, stream>>>(node_index, timestamp, counts, ts_bits, E);
    scan_block_sums<<<SCAN_B, SCAN_B, 0, stream>>>(counts, partial);
    scan_top<<<1, SCAN_B, 0, stream>>>(partial, base);
    scan_final<<<SCAN_B, SCAN_B, 0, stream>>>(counts, base, ofs, cursor);
    scatter_idx_kernel<<<eblocks, 256, 0, stream>>>(node_index, cursor, sorted, E);
    reduce_kernel<<<N_NODES / 4, 256, 0, stream>>>((const float4*)messages, sorted,
                                                   ofs, counts, out);
}